// Round 17
// baseline (190.522 us; speedup 1.0000x reference)
//
#include <hip/hip_runtime.h>
#include <stdint.h>

typedef float  f32x4  __attribute__((ext_vector_type(4)));
typedef float  float4v __attribute__((ext_vector_type(4)));
typedef int    i32x4  __attribute__((ext_vector_type(4)));
typedef int    i32x8  __attribute__((ext_vector_type(8)));
typedef unsigned int u32x4 __attribute__((ext_vector_type(4)));

#define BM 128
#define BN 256
#define BKB 128   // fp8 bytes (=elements) per K-tile

// ---- f32 (pre-clamped to [-448,448]) -> OCP e4m3fn byte, RNE (matches ml_dtypes) ----
__device__ __forceinline__ unsigned f32_to_e4m3_sw(float t) {
    unsigned u = __float_as_uint(t);
    unsigned s = (u >> 24) & 0x80u;
    float ax = fabsf(t);
    if (ax < 0.015625f) {
        int m = (int)rintf(ax * 512.0f);
        return s | (unsigned)m;
    }
    unsigned au = u & 0x7fffffffu;
    unsigned r = au + 0x7FFFFu + ((au >> 20) & 1u);
    return s | (((r >> 23) - 120u) << 3) | ((r >> 20) & 7u);
}

__device__ __forceinline__ unsigned pack4_e4m3(float a, float b, float c, float d) {
#if __has_builtin(__builtin_amdgcn_cvt_pk_fp8_f32)
    int v = 0;
    v = __builtin_amdgcn_cvt_pk_fp8_f32(a, b, v, false);
    v = __builtin_amdgcn_cvt_pk_fp8_f32(c, d, v, true);
    return (unsigned)v;
#else
    return f32_to_e4m3_sw(a) | (f32_to_e4m3_sw(b) << 8) |
           (f32_to_e4m3_sw(c) << 16) | (f32_to_e4m3_sw(d) << 24);
#endif
}

// ---- merged quant: x (scale+clamp+round) then w (exact convert), one launch ----
// Nontemporal loads: the f32 inputs stream once and are never re-read; keep
// L2/LLC capacity for the fp8 outputs that the GEMM re-reads.
__global__ void quant_kernel(const float4v* __restrict__ x, u32x4* __restrict__ xout, long nx16,
                             const float4v* __restrict__ w, u32x4* __restrict__ wout, long nw16,
                             const float* __restrict__ in_scale) {
    const float inv = 1.0f / in_scale[0];
    const long stride = (long)gridDim.x * blockDim.x;
    long i0 = (long)blockIdx.x * blockDim.x + threadIdx.x;
    for (long i = i0; i < nx16; i += stride) {
        u32x4 q;
#pragma unroll
        for (int j = 0; j < 4; ++j) {
            float4v v = __builtin_nontemporal_load(&x[i * 4 + j]);
            float t0 = fminf(fmaxf(v[0] * inv, -448.0f), 448.0f);
            float t1 = fminf(fmaxf(v[1] * inv, -448.0f), 448.0f);
            float t2 = fminf(fmaxf(v[2] * inv, -448.0f), 448.0f);
            float t3 = fminf(fmaxf(v[3] * inv, -448.0f), 448.0f);
            q[j] = pack4_e4m3(t0, t1, t2, t3);
        }
        xout[i] = q;
    }
    for (long i = i0; i < nw16; i += stride) {
        u32x4 q;
#pragma unroll
        for (int j = 0; j < 4; ++j) {
            float4v v = __builtin_nontemporal_load(&w[i * 4 + j]);
            q[j] = pack4_e4m3(v[0], v[1], v[2], v[3]);
        }
        wout[i] = q;
    }
}

// ===== R13/R15 GEMM (best: 135.5 us, MfmaUtil 44.5%, 0 bank conflicts) =====
// 128x256, 4 waves (2M x 2N), per-wave 64x128, acc[4][8]. LDS A 16K + B 32K = 48 KB,
// 2 blocks/CU (RF-saturated: 2x4x~240 = 1920/2048 VGPR). sigma-swizzle: granule j at
// slot pi(j)=(j>>1)+4*(j&1) XOR (row&7); lane g reads slots g^sw,(g^sw)^4 (0 conflicts).
// ONLY change this round: nontemporal C stores — keep the 132 MB C stream from
// evicting A/B panels in L2, shortening the exposed vmcnt(0) staging drains.

__global__ __launch_bounds__(256, 2) void gemm_kernel(
    const unsigned char* __restrict__ A,   // [M,K] e4m3 bytes
    const unsigned char* __restrict__ W,   // [N,K] e4m3 bytes
    const float* __restrict__ bias,
    const float* __restrict__ in_scale,
    const float* __restrict__ w_scale,
    float* __restrict__ C, int M, int N, int K)
{
    __shared__ __align__(16) unsigned char sA[BM * BKB];  // 16 KB
    __shared__ __align__(16) unsigned char sB[BN * BKB];  // 32 KB

    const int tid  = threadIdx.x;
    const int wave = tid >> 6;
    const int lane = tid & 63;
    const int wr   = wave >> 1;    // 0..1: rows 64 each
    const int wc   = wave & 1;     // 0..1: cols 128 each

    // XCD-aware bijective swizzle (1024 % 8 == 0)
    const int nwg = gridDim.x;
    int bid = blockIdx.x, wgid;
    if ((nwg & 7) == 0) { const int cpx = nwg >> 3; wgid = (bid & 7) * cpx + (bid >> 3); }
    else wgid = bid;
    const int ntn  = N / BN;
    const int brow = (wgid / ntn) * BM;
    const int bcol = (wgid % ntn) * BN;

    // sigma-swizzled staging: phys slot (lane&7) holds granule pi^-1((lane&7)^(lane>>3)):
    //   p = (lane&7)^(lane>>3);  slotSrc = 2*(p&3) + (p>>2)
    const int rowInChunk = lane >> 3;
    const int pPhys      = (lane & 7) ^ rowInChunk;
    const int slotSrc    = 2 * (pPhys & 3) + (pPhys >> 2);

    f32x4 acc[4][8];
#pragma unroll
    for (int i = 0; i < 4; ++i)
#pragma unroll
        for (int j = 0; j < 8; ++j) { f32x4 z = {0.f,0.f,0.f,0.f}; acc[i][j] = z; }

    const int g = lane >> 4;   // k-group 0..3: lane covers k bytes [g*32, g*32+32)

    for (int kt = 0; kt < K; kt += BKB) {
        if (kt) __syncthreads();
        // stage A: 16 chunks (4/wave); B: 32 chunks (8/wave). 12 loads/thread.
#pragma unroll
        for (int c = 0; c < 4; ++c) {
            const int chunk = wave * 4 + c;
            const int row   = chunk * 8 + rowInChunk;
            const unsigned char* ga = A + (long)(brow + row) * K + kt + slotSrc * 16;
            __builtin_amdgcn_global_load_lds(
                (const __attribute__((address_space(1))) unsigned int*)ga,
                (__attribute__((address_space(3))) unsigned int*)(sA + chunk * 1024), 16, 0, 0);
        }
#pragma unroll
        for (int c = 0; c < 8; ++c) {
            const int chunk = wave * 8 + c;
            const int row   = chunk * 8 + rowInChunk;
            const unsigned char* gb = W + (long)(bcol + row) * K + kt + slotSrc * 16;
            __builtin_amdgcn_global_load_lds(
                (const __attribute__((address_space(1))) unsigned int*)gb,
                (__attribute__((address_space(3))) unsigned int*)(sB + chunk * 1024), 16, 0, 0);
        }
        __syncthreads();

        i32x8 af[4];
#pragma unroll
        for (int mi = 0; mi < 4; ++mi) {
            const int row = wr * 64 + mi * 16 + (lane & 15);
            const int sl  = g ^ (row & 7);          // lo slot: granule 2g
            i32x4 lo = *(const i32x4*)(sA + row * 128 + sl * 16);
            i32x4 hi = *(const i32x4*)(sA + row * 128 + (sl ^ 4) * 16);  // granule 2g+1
            i32x8 t;
            t[0]=lo[0]; t[1]=lo[1]; t[2]=lo[2]; t[3]=lo[3];
            t[4]=hi[0]; t[5]=hi[1]; t[6]=hi[2]; t[7]=hi[3];
            af[mi] = t;
        }
#pragma unroll
        for (int ni = 0; ni < 8; ++ni) {
            const int row = wc * 128 + ni * 16 + (lane & 15);
            const int sl  = g ^ (row & 7);
            i32x4 lo = *(const i32x4*)(sB + row * 128 + sl * 16);
            i32x4 hi = *(const i32x4*)(sB + row * 128 + (sl ^ 4) * 16);
            i32x8 bf;
            bf[0]=lo[0]; bf[1]=lo[1]; bf[2]=lo[2]; bf[3]=lo[3];
            bf[4]=hi[0]; bf[5]=hi[1]; bf[6]=hi[2]; bf[7]=hi[3];
#pragma unroll
            for (int mi = 0; mi < 4; ++mi)
                acc[mi][ni] = __builtin_amdgcn_mfma_scale_f32_16x16x128_f8f6f4(
                    af[mi], bf, acc[mi][ni],
                    0, 0, 0, 0x7F7F7F7F, 0, 0x7F7F7F7F);
        }
    }

    // epilogue: out = acc * (s_in*s_w) + bias; nontemporal stores (C is never re-read)
    const float sc = in_scale[0] * w_scale[0];
#pragma unroll
    for (int ni = 0; ni < 8; ++ni) {
        const int n   = bcol + wc * 128 + ni * 16 + (lane & 15);
        const float bv = bias[n];
#pragma unroll
        for (int mi = 0; mi < 4; ++mi) {
            const int m0 = brow + wr * 64 + mi * 16 + ((lane >> 4) << 2);
#pragma unroll
            for (int r = 0; r < 4; ++r)
                __builtin_nontemporal_store(fmaf(acc[mi][ni][r], sc, bv),
                                            &C[(long)(m0 + r) * N + n]);
        }
    }
}

extern "C" void kernel_launch(void* const* d_in, const int* in_sizes, int n_in,
                              void* d_out, int out_size, void* d_ws, size_t ws_size,
                              hipStream_t stream) {
    const float* x    = (const float*)d_in[0];   // [B,S,IN] f32
    const float* w    = (const float*)d_in[1];   // [OUT,IN] f32 (e4m3-exact values)
    const float* bias = (const float*)d_in[2];   // [OUT]
    const float* in_s = (const float*)d_in[3];   // [1]
    const float* w_s  = (const float*)d_in[4];   // [1]
    float* out = (float*)d_out;                  // [B,S,OUT]

    const int  N   = in_sizes[2];                // 4096
    const long wsz = (long)in_sizes[1];
    const int  K   = (int)(wsz / N);             // 4096
    const long xsz = (long)in_sizes[0];
    const int  M   = (int)(xsz / K);             // 8192

    unsigned char* xq = (unsigned char*)d_ws;    // M*K e4m3 bytes
    unsigned char* wq = xq + (size_t)M * K;      // N*K e4m3 bytes

    quant_kernel<<<2048, 256, 0, stream>>>((const float4v*)x, (u32x4*)xq, xsz / 16,
                                           (const float4v*)w, (u32x4*)wq, wsz / 16, in_s);

    dim3 grid((M / BM) * (N / BN));              // 64*16 = 1024 blocks, %8==0
    gemm_kernel<<<grid, 256, 0, stream>>>(xq, wq, bias, in_s, w_s, out, M, N, K);
}

// Round 18
// 163.459 us; speedup vs baseline: 1.1656x; 1.1656x over previous
//
#include <hip/hip_runtime.h>
#include <stdint.h>

typedef float  f32x4  __attribute__((ext_vector_type(4)));
typedef float  float4v __attribute__((ext_vector_type(4)));
typedef int    i32x4  __attribute__((ext_vector_type(4)));
typedef int    i32x8  __attribute__((ext_vector_type(8)));
typedef unsigned int u32x4 __attribute__((ext_vector_type(4)));

#define BM 128
#define BN 256
#define BKB 128   // fp8 bytes (=elements) per K-tile

// ---- f32 (pre-clamped to [-448,448]) -> OCP e4m3fn byte, RNE (matches ml_dtypes) ----
__device__ __forceinline__ unsigned f32_to_e4m3_sw(float t) {
    unsigned u = __float_as_uint(t);
    unsigned s = (u >> 24) & 0x80u;
    float ax = fabsf(t);
    if (ax < 0.015625f) {
        int m = (int)rintf(ax * 512.0f);
        return s | (unsigned)m;
    }
    unsigned au = u & 0x7fffffffu;
    unsigned r = au + 0x7FFFFu + ((au >> 20) & 1u);
    return s | (((r >> 23) - 120u) << 3) | ((r >> 20) & 7u);
}

__device__ __forceinline__ unsigned pack4_e4m3(float a, float b, float c, float d) {
#if __has_builtin(__builtin_amdgcn_cvt_pk_fp8_f32)
    int v = 0;
    v = __builtin_amdgcn_cvt_pk_fp8_f32(a, b, v, false);
    v = __builtin_amdgcn_cvt_pk_fp8_f32(c, d, v, true);
    return (unsigned)v;
#else
    return f32_to_e4m3_sw(a) | (f32_to_e4m3_sw(b) << 8) |
           (f32_to_e4m3_sw(c) << 16) | (f32_to_e4m3_sw(d) << 24);
#endif
}

// ---- merged quant (R15 version: PLAIN loads — NT loads cost ~24 us in R17) ----
__global__ void quant_kernel(const float4v* __restrict__ x, u32x4* __restrict__ xout, long nx16,
                             const float4v* __restrict__ w, u32x4* __restrict__ wout, long nw16,
                             const float* __restrict__ in_scale) {
    const float inv = 1.0f / in_scale[0];
    const long stride = (long)gridDim.x * blockDim.x;
    long i0 = (long)blockIdx.x * blockDim.x + threadIdx.x;
    for (long i = i0; i < nx16; i += stride) {
        u32x4 q;
#pragma unroll
        for (int j = 0; j < 4; ++j) {
            float4v v = x[i * 4 + j];
            float t0 = fminf(fmaxf(v[0] * inv, -448.0f), 448.0f);
            float t1 = fminf(fmaxf(v[1] * inv, -448.0f), 448.0f);
            float t2 = fminf(fmaxf(v[2] * inv, -448.0f), 448.0f);
            float t3 = fminf(fmaxf(v[3] * inv, -448.0f), 448.0f);
            q[j] = pack4_e4m3(t0, t1, t2, t3);
        }
        xout[i] = q;
    }
    for (long i = i0; i < nw16; i += stride) {
        u32x4 q;
#pragma unroll
        for (int j = 0; j < 4; ++j) {
            float4v v = w[i * 4 + j];
            q[j] = pack4_e4m3(v[0], v[1], v[2], v[3]);
        }
        wout[i] = q;
    }
}

// ===== R17 GEMM (best: ~131.5 us, MfmaUtil 46%, 0 bank conflicts) — unchanged =====
// 128x256, 4 waves (2M x 2N), per-wave 64x128, acc[4][8]. LDS A 16K + B 32K = 48 KB,
// 2 blocks/CU (RF-saturated). sigma-swizzle: granule j at slot pi(j)=(j>>1)+4*(j&1)
// XOR (row&7); lane g reads slots g^sw,(g^sw)^4 (0 conflicts). NT C-stores keep the
// C stream from evicting A/B panels in L2 (R17: GEMM 135.5 -> 131.5, MfmaUtil +1.5).

__global__ __launch_bounds__(256, 2) void gemm_kernel(
    const unsigned char* __restrict__ A,   // [M,K] e4m3 bytes
    const unsigned char* __restrict__ W,   // [N,K] e4m3 bytes
    const float* __restrict__ bias,
    const float* __restrict__ in_scale,
    const float* __restrict__ w_scale,
    float* __restrict__ C, int M, int N, int K)
{
    __shared__ __align__(16) unsigned char sA[BM * BKB];  // 16 KB
    __shared__ __align__(16) unsigned char sB[BN * BKB];  // 32 KB

    const int tid  = threadIdx.x;
    const int wave = tid >> 6;
    const int lane = tid & 63;
    const int wr   = wave >> 1;    // 0..1: rows 64 each
    const int wc   = wave & 1;     // 0..1: cols 128 each

    // XCD-aware bijective swizzle (1024 % 8 == 0)
    const int nwg = gridDim.x;
    int bid = blockIdx.x, wgid;
    if ((nwg & 7) == 0) { const int cpx = nwg >> 3; wgid = (bid & 7) * cpx + (bid >> 3); }
    else wgid = bid;
    const int ntn  = N / BN;
    const int brow = (wgid / ntn) * BM;
    const int bcol = (wgid % ntn) * BN;

    // sigma-swizzled staging: phys slot (lane&7) holds granule pi^-1((lane&7)^(lane>>3)):
    //   p = (lane&7)^(lane>>3);  slotSrc = 2*(p&3) + (p>>2)
    const int rowInChunk = lane >> 3;
    const int pPhys      = (lane & 7) ^ rowInChunk;
    const int slotSrc    = 2 * (pPhys & 3) + (pPhys >> 2);

    f32x4 acc[4][8];
#pragma unroll
    for (int i = 0; i < 4; ++i)
#pragma unroll
        for (int j = 0; j < 8; ++j) { f32x4 z = {0.f,0.f,0.f,0.f}; acc[i][j] = z; }

    const int g = lane >> 4;   // k-group 0..3: lane covers k bytes [g*32, g*32+32)

    for (int kt = 0; kt < K; kt += BKB) {
        if (kt) __syncthreads();
        // stage A: 16 chunks (4/wave); B: 32 chunks (8/wave). 12 loads/thread.
#pragma unroll
        for (int c = 0; c < 4; ++c) {
            const int chunk = wave * 4 + c;
            const int row   = chunk * 8 + rowInChunk;
            const unsigned char* ga = A + (long)(brow + row) * K + kt + slotSrc * 16;
            __builtin_amdgcn_global_load_lds(
                (const __attribute__((address_space(1))) unsigned int*)ga,
                (__attribute__((address_space(3))) unsigned int*)(sA + chunk * 1024), 16, 0, 0);
        }
#pragma unroll
        for (int c = 0; c < 8; ++c) {
            const int chunk = wave * 8 + c;
            const int row   = chunk * 8 + rowInChunk;
            const unsigned char* gb = W + (long)(bcol + row) * K + kt + slotSrc * 16;
            __builtin_amdgcn_global_load_lds(
                (const __attribute__((address_space(1))) unsigned int*)gb,
                (__attribute__((address_space(3))) unsigned int*)(sB + chunk * 1024), 16, 0, 0);
        }
        __syncthreads();

        i32x8 af[4];
#pragma unroll
        for (int mi = 0; mi < 4; ++mi) {
            const int row = wr * 64 + mi * 16 + (lane & 15);
            const int sl  = g ^ (row & 7);          // lo slot: granule 2g
            i32x4 lo = *(const i32x4*)(sA + row * 128 + sl * 16);
            i32x4 hi = *(const i32x4*)(sA + row * 128 + (sl ^ 4) * 16);  // granule 2g+1
            i32x8 t;
            t[0]=lo[0]; t[1]=lo[1]; t[2]=lo[2]; t[3]=lo[3];
            t[4]=hi[0]; t[5]=hi[1]; t[6]=hi[2]; t[7]=hi[3];
            af[mi] = t;
        }
#pragma unroll
        for (int ni = 0; ni < 8; ++ni) {
            const int row = wc * 128 + ni * 16 + (lane & 15);
            const int sl  = g ^ (row & 7);
            i32x4 lo = *(const i32x4*)(sB + row * 128 + sl * 16);
            i32x4 hi = *(const i32x4*)(sB + row * 128 + (sl ^ 4) * 16);
            i32x8 bf;
            bf[0]=lo[0]; bf[1]=lo[1]; bf[2]=lo[2]; bf[3]=lo[3];
            bf[4]=hi[0]; bf[5]=hi[1]; bf[6]=hi[2]; bf[7]=hi[3];
#pragma unroll
            for (int mi = 0; mi < 4; ++mi)
                acc[mi][ni] = __builtin_amdgcn_mfma_scale_f32_16x16x128_f8f6f4(
                    af[mi], bf, acc[mi][ni],
                    0, 0, 0, 0x7F7F7F7F, 0, 0x7F7F7F7F);
        }
    }

    // epilogue: out = acc * (s_in*s_w) + bias; nontemporal stores (C never re-read)
    const float sc = in_scale[0] * w_scale[0];
#pragma unroll
    for (int ni = 0; ni < 8; ++ni) {
        const int n   = bcol + wc * 128 + ni * 16 + (lane & 15);
        const float bv = bias[n];
#pragma unroll
        for (int mi = 0; mi < 4; ++mi) {
            const int m0 = brow + wr * 64 + mi * 16 + ((lane >> 4) << 2);
#pragma unroll
            for (int r = 0; r < 4; ++r)
                __builtin_nontemporal_store(fmaf(acc[mi][ni][r], sc, bv),
                                            &C[(long)(m0 + r) * N + n]);
        }
    }
}

extern "C" void kernel_launch(void* const* d_in, const int* in_sizes, int n_in,
                              void* d_out, int out_size, void* d_ws, size_t ws_size,
                              hipStream_t stream) {
    const float* x    = (const float*)d_in[0];   // [B,S,IN] f32
    const float* w    = (const float*)d_in[1];   // [OUT,IN] f32 (e4m3-exact values)
    const float* bias = (const float*)d_in[2];   // [OUT]
    const float* in_s = (const float*)d_in[3];   // [1]
    const float* w_s  = (const float*)d_in[4];   // [1]
    float* out = (float*)d_out;                  // [B,S,OUT]

    const int  N   = in_sizes[2];                // 4096
    const long wsz = (long)in_sizes[1];
    const int  K   = (int)(wsz / N);             // 4096
    const long xsz = (long)in_sizes[0];
    const int  M   = (int)(xsz / K);             // 8192

    unsigned char* xq = (unsigned char*)d_ws;    // M*K e4m3 bytes
    unsigned char* wq = xq + (size_t)M * K;      // N*K e4m3 bytes

    quant_kernel<<<2048, 256, 0, stream>>>((const float4v*)x, (u32x4*)xq, xsz / 16,
                                           (const float4v*)w, (u32x4*)wq, wsz / 16, in_s);

    dim3 grid((M / BM) * (N / BN));              // 64*16 = 1024 blocks, %8==0
    gemm_kernel<<<grid, 256, 0, stream>>>(xq, wq, bias, in_s, w_s, out, M, N, K);
}